// Round 6
// baseline (338.130 us; speedup 1.0000x reference)
//
#include <hip/hip_runtime.h>

// PNN fused, round 6: barrier-free max-occupancy gather.
//
// Kernel 1 (pnn_stage): NO LDS, NO barriers. One thread per (b, f) task
//   (638,976 tasks, 2496 blocks x 256). g = blk*256+tid; b = g & 16383,
//   f = g >> 14 (f block-uniform -> scalar table base). Thread: load idx/xv,
//   4 x 16B of table row, cvt f16 + scale, store two 16B pieces directly to
//   Aws in MFMA fragment order (16 lanes -> 256B contiguous runs).
//   +20 blocks convert weights to B-fragment order (verified round 4/5).
//   +128 blocks zero the K-pad (kstep 19, lanes 32..63 of each rowtile).
//   Occupancy: 32 VGPR, no LDS -> 32 waves/CU (2x round 5's gather).
//
// Kernel 2 (pnn_gemm): unchanged (verified): K-loop = 2 coalesced dwordx4 +
//   mfma_f32_16x16x32_f16 x20, then fused fp32 MLP in LDS.

namespace {

typedef _Float16 half8 __attribute__((ext_vector_type(8)));
typedef float floatx4 __attribute__((ext_vector_type(4)));
typedef float f32x4 __attribute__((ext_vector_type(4)));

constexpr int Bn = 16384;
constexpr int Fn = 39;
constexpr int Vn = 100000;
constexpr int En = 16;
constexpr int M = 32;                 // rows per gemm block
constexpr int KST = 20;               // k-steps of 32 (624 padded to 640)
constexpr int AWS_OFF_H = 65536;      // Aws offset in halfs (byte 131072)

constexpr int GB = (Bn * Fn) / 256;   // 2496 gather blocks
constexpr int WBLOCKS = 20;           // weight-conversion blocks (5120 slots)
constexpr int ZBLOCKS = 128;          // K-pad zero blocks (32768 x 16B slots)

__device__ __forceinline__ half8 cvt8(float4 a, float4 b) {
    half8 h;
    h[0] = (_Float16)a.x; h[1] = (_Float16)a.y;
    h[2] = (_Float16)a.z; h[3] = (_Float16)a.w;
    h[4] = (_Float16)b.x; h[5] = (_Float16)b.y;
    h[6] = (_Float16)b.z; h[7] = (_Float16)b.w;
    return h;
}

__device__ __forceinline__ half8 cvt8s(f32x4 a, f32x4 b, float s) {
    half8 h;
    h[0] = (_Float16)(a[0] * s); h[1] = (_Float16)(a[1] * s);
    h[2] = (_Float16)(a[2] * s); h[3] = (_Float16)(a[3] * s);
    h[4] = (_Float16)(b[0] * s); h[5] = (_Float16)(b[1] * s);
    h[6] = (_Float16)(b[2] * s); h[7] = (_Float16)(b[3] * s);
    return h;
}

// ---------------- Kernel 1: stage A (gather) + stage W + zero pad ----------------
__global__ __launch_bounds__(256) void pnn_stage(
    const int* __restrict__ Xi,
    const float* __restrict__ Xv,
    const float* __restrict__ T,
    const float* __restrict__ w_first,
    const float* __restrict__ w_inner,
    _Float16* __restrict__ ws)
{
    _Float16* __restrict__ Wws = ws;               // 5120*8 halfs = 80 KB
    _Float16* __restrict__ Aws = ws + AWS_OFF_H;   // 1024*20*512 halfs = 21 MB

    const int tid = threadIdx.x;
    const int blk = blockIdx.x;

    if (blk >= GB) {
        if (blk < GB + WBLOCKS) {
            // ---- weight conversion (verified) ----
            const int slot = (blk - GB) * 256 + tid;            // 0..5119
            const int t16 = slot / (KST * 64);
            const int rem = slot % (KST * 64);
            const int t = rem >> 6;
            const int lane = rem & 63;
            const int n = t16 * 16 + (lane & 15);
            const int kb = t * 32 + (lane >> 4) * 8;
            half8 h = {0, 0, 0, 0, 0, 0, 0, 0};
            if (!(t == KST - 1 && (lane >> 4) >= 2)) {   // kb<=616 fully valid
                const float* src = ((n < 32) ? (w_first + (size_t)n * 624)
                                             : (w_inner + (size_t)(n - 32) * 624)) + kb;
                const float4 a = *reinterpret_cast<const float4*>(src);
                const float4 b = *reinterpret_cast<const float4*>(src + 4);
                h = cvt8(a, b);
            }
            *reinterpret_cast<half8*>(Wws + (size_t)slot * 8) = h;
        } else {
            // ---- K-pad zero: kstep 19, lanes 32..63 of each rowtile ----
            const int j = (blk - GB - WBLOCKS) * 256 + tid;     // 0..32767
            const int rt = j >> 5, s = j & 31;
            half8 z = {0, 0, 0, 0, 0, 0, 0, 0};
            *reinterpret_cast<half8*>(
                Aws + (size_t)rt * (KST * 512) + (KST - 1) * 512 + 256 + s * 8) = z;
        }
        return;
    }

    // ---- gather: one (b, f) per thread, barrier-free ----
    const int g = blk * 256 + tid;
    const int b = g & (Bn - 1);
    const int f = g >> 14;            // block-uniform (except boundary blocks)

    const int idx = Xi[b * Fn + f];
    const float s = Xv[b * Fn + f];

    const f32x4* src = reinterpret_cast<const f32x4*>(
        T + ((size_t)f * Vn + (size_t)idx) * En);
    const f32x4 q0 = __builtin_nontemporal_load(src);
    const f32x4 q1 = __builtin_nontemporal_load(src + 1);
    const f32x4 q2 = __builtin_nontemporal_load(src + 2);
    const f32x4 q3 = __builtin_nontemporal_load(src + 3);

    // fragment slot: rowtile rt = b>>4, r = b&15;
    // base halfs = rt*10240 + (f>>1)*512 + (f&1)*256 + r*8 ; piece1 at +128
    const int rt = b >> 4, r = b & 15;
    _Float16* dst = Aws + (size_t)rt * (KST * 512)
                    + (f >> 1) * 512 + (f & 1) * 256 + r * 8;
    *reinterpret_cast<half8*>(dst)       = cvt8s(q0, q1, s);
    *reinterpret_cast<half8*>(dst + 128) = cvt8s(q2, q3, s);
}

// ---------------- Kernel 2: GEMM + fused MLP (verified) ----------------
struct SMemE {
    float x[M * 69];     // x[row][d], stride 69 -> conflict-free
    float wsh[2176];     // lin1_W[0..1023] lin2_W[1024..2047] b1@2048 b2@2080 lastW@2112 lastb@2144
    float r1[1024];
    float r2[1024];
};

__global__ __launch_bounds__(512) void pnn_gemm(
    const _Float16* __restrict__ ws,
    const float* __restrict__ lin1_W,
    const float* __restrict__ lin1_b,
    const float* __restrict__ lin2_W,
    const float* __restrict__ lin2_b,
    const float* __restrict__ last_W,
    const float* __restrict__ last_b,
    float* __restrict__ out)
{
    __shared__ SMemE sm;

    const _Float16* __restrict__ Wws = ws;
    const _Float16* __restrict__ Aws = ws + AWS_OFF_H;

    const int tid = threadIdx.x;
    const int lane = tid & 63;
    const int wv = tid >> 6;
    const int q = wv & 1;        // row-half (16 rows)
    const int t16 = wv >> 1;     // col-tile (16 cols)
    const int row0 = blockIdx.x * M;

    const _Float16* aptr = Aws + ((size_t)(blockIdx.x * 2 + q) * KST) * 512 + lane * 8;
    const _Float16* bptr = Wws + ((size_t)t16 * KST) * 512 + lane * 8;

    floatx4 acc = {0.0f, 0.0f, 0.0f, 0.0f};
#pragma unroll
    for (int t = 0; t < KST; ++t) {
        const half8 af = *reinterpret_cast<const half8*>(aptr + t * 512);
        const half8 bf = *reinterpret_cast<const half8*>(bptr + t * 512);
        acc = __builtin_amdgcn_mfma_f32_16x16x32_f16(af, bf, acc, 0, 0, 0);
    }

    // ---- write C tile: col=lane&15, row=(lane>>4)*4+reg ----
    {
        const int col = t16 * 16 + (lane & 15);
        const int rbase = q * 16 + (lane >> 4) * 4;
#pragma unroll
        for (int r = 0; r < 4; ++r)
            sm.x[(rbase + r) * 69 + col] = acc[r];
    }

    // ---- stage MLP weights ----
    for (int i = tid; i < 2145; i += 512) {
        float v;
        if (i < 1024)      v = lin1_W[i];
        else if (i < 2048) v = lin2_W[i - 1024];
        else if (i < 2080) v = lin1_b[i - 2048];
        else if (i < 2112) v = lin2_b[i - 2080];
        else if (i < 2144) v = last_W[i - 2112];
        else               v = last_b[0];
        sm.wsh[i] = v;
    }
    __syncthreads();

    // ---- xin[j][r] = first + s^2 ----
    for (int p = tid; p < 1024; p += 512) {
        const int j = p >> 5, r = p & 31;
        const float fi = sm.x[r * 69 + j];
        const float sq = sm.x[r * 69 + 32 + j];
        sm.r1[j * 32 + r] = fi + sq * sq;
    }
    __syncthreads();

    // ---- layer 1 ----
    {
        const int r = tid & 31, n0 = (tid >> 5) * 2;
        float a0 = sm.wsh[2048 + n0];
        float a1 = sm.wsh[2048 + n0 + 1];
#pragma unroll
        for (int j = 0; j < 32; ++j) {
            const float xj = sm.r1[j * 32 + r];
            a0 = fmaf(sm.wsh[n0 * 32 + j],       xj, a0);
            a1 = fmaf(sm.wsh[(n0 + 1) * 32 + j], xj, a1);
        }
        sm.r2[n0 * 32 + r]       = fmaxf(a0, 0.0f);
        sm.r2[(n0 + 1) * 32 + r] = fmaxf(a1, 0.0f);
    }
    __syncthreads();

    // ---- layer 2 ----
    {
        const int r = tid & 31, n0 = (tid >> 5) * 2;
        float a0 = sm.wsh[2080 + n0];
        float a1 = sm.wsh[2080 + n0 + 1];
#pragma unroll
        for (int j = 0; j < 32; ++j) {
            const float xj = sm.r2[j * 32 + r];
            a0 = fmaf(sm.wsh[1024 + n0 * 32 + j],       xj, a0);
            a1 = fmaf(sm.wsh[1024 + (n0 + 1) * 32 + j], xj, a1);
        }
        sm.r1[n0 * 32 + r]       = fmaxf(a0, 0.0f);
        sm.r1[(n0 + 1) * 32 + r] = fmaxf(a1, 0.0f);
    }
    __syncthreads();

    // ---- last layer + store ----
    if (tid < M) {
        float res = sm.wsh[2144];
#pragma unroll
        for (int j = 0; j < 32; ++j)
            res = fmaf(sm.wsh[2112 + j], sm.r1[j * 32 + tid], res);
        out[row0 + tid] = res;
    }
}

} // namespace

extern "C" void kernel_launch(void* const* d_in, const int* in_sizes, int n_in,
                              void* d_out, int out_size, void* d_ws, size_t ws_size,
                              hipStream_t stream) {
    (void)in_sizes; (void)n_in; (void)out_size; (void)ws_size;
    const int*   Xi      = (const int*)d_in[0];
    const float* Xv      = (const float*)d_in[1];
    const float* T       = (const float*)d_in[2];
    const float* w_first = (const float*)d_in[3];
    const float* w_inner = (const float*)d_in[4];
    const float* lin1_W  = (const float*)d_in[5];
    const float* lin1_b  = (const float*)d_in[6];
    const float* lin2_W  = (const float*)d_in[7];
    const float* lin2_b  = (const float*)d_in[8];
    const float* last_W  = (const float*)d_in[9];
    const float* last_b  = (const float*)d_in[10];
    float* out = (float*)d_out;
    _Float16* ws = (_Float16*)d_ws;

    hipLaunchKernelGGL(pnn_stage, dim3(GB + WBLOCKS + ZBLOCKS), dim3(256), 0, stream,
                       Xi, Xv, T, w_first, w_inner, ws);
    hipLaunchKernelGGL(pnn_gemm, dim3(Bn / M), dim3(512), 0, stream,
                       ws, lin1_W, lin1_b, lin2_W, lin2_b, last_W, last_b, out);
}

// Round 7
// 324.272 us; speedup vs baseline: 1.0427x; 1.0427x over previous
//
#include <hip/hip_runtime.h>

// PNN fused, round 7: single fused kernel (no workspace round-trip).
//
// 512 blocks x 512 threads; block owns M=32 rows (2 rowtiles of 16).
// Phase 1: stage xi/xv coalesced; gather 1248 random 64B table lines with the
//   round-5-verified shape (4 consecutive lanes = 4 x 16B chunks of one line,
//   two 5-deep register batches), scale+cvt f16, write straight into LDS in
//   MFMA A-fragment order At[tile(2)][kstep(20)][lane(64)][8]. K-pad zeroed.
// Phase 2: per wave (q=rowtile, t16=col-tile) 20 k-steps of
//   mfma_f32_16x16x32_f16; A-frag = conflict-free ds_read_b128; B-frag from
//   global fp32 weights (k-clamped at ragged tail, A-pad zero there) + cvt.
// Phase 3: verified fused fp32 MLP epilogue in LDS (union over At).
//
// LDS ~50 KB -> 3 blocks/CU; __launch_bounds__(512,6) caps VGPR at 85.

namespace {

typedef _Float16 half8 __attribute__((ext_vector_type(8)));
typedef _Float16 half4 __attribute__((ext_vector_type(4)));
typedef float floatx4 __attribute__((ext_vector_type(4)));
typedef float f32x4 __attribute__((ext_vector_type(4)));

constexpr int Bn = 16384;
constexpr int Fn = 39;
constexpr int Vn = 100000;
constexpr int En = 16;
constexpr int M = 32;                 // rows per block
constexpr int KST = 20;               // k-steps of 32 (624 padded to 640)
constexpr int THREADS = 512;
constexpr int TILE_H = KST * 512;     // halfs per 16-row fragment tile (10240)

union SMem {
    struct {
        __align__(16) _Float16 At[2 * TILE_H];  // 40 KB, fragment order
        __align__(16) int   xi[M * Fn];         // 4992 B
        __align__(16) float xv[M * Fn];         // 4992 B
    } g;
    struct {
        _Float16 At_pad[2 * TILE_H];            // overlay (A dead in epilogue)
        float x[M * 69];     // x[row][d], stride 69 -> conflict-free
        float wsh[2176];     // l1W[0..1023] l2W[1024..2047] b1@2048 b2@2080 lW@2112 lb@2144
        float r1[1024];
        float r2[1024];
    } e;
};

__device__ __forceinline__ half4 cvt4s(f32x4 a, float s) {
    half4 h;
    h[0] = (_Float16)(a[0] * s);
    h[1] = (_Float16)(a[1] * s);
    h[2] = (_Float16)(a[2] * s);
    h[3] = (_Float16)(a[3] * s);
    return h;
}

__device__ __forceinline__ half8 cvt8(float4 a, float4 b) {
    half8 h;
    h[0] = (_Float16)a.x; h[1] = (_Float16)a.y;
    h[2] = (_Float16)a.z; h[3] = (_Float16)a.w;
    h[4] = (_Float16)b.x; h[5] = (_Float16)b.y;
    h[6] = (_Float16)b.z; h[7] = (_Float16)b.w;
    return h;
}

__global__ __launch_bounds__(THREADS, 6) void pnn_fused(
    const int* __restrict__ Xi,
    const float* __restrict__ Xv,
    const float* __restrict__ T,
    const float* __restrict__ w_first,
    const float* __restrict__ w_inner,
    const float* __restrict__ lin1_W,
    const float* __restrict__ lin1_b,
    const float* __restrict__ lin2_W,
    const float* __restrict__ lin2_b,
    const float* __restrict__ last_W,
    const float* __restrict__ last_b,
    float* __restrict__ out)
{
    __shared__ SMem sm;

    const int tid = threadIdx.x;
    const int lane = tid & 63;
    const int wv = tid >> 6;
    const int row0 = blockIdx.x * M;

    // ---- stage xi/xv coalesced (1248 each = 312 x int4/float4) ----
    if (tid < 312) {
        reinterpret_cast<int4*>(sm.g.xi)[tid] =
            reinterpret_cast<const int4*>(Xi + (size_t)row0 * Fn)[tid];
        reinterpret_cast<float4*>(sm.g.xv)[tid] =
            reinterpret_cast<const float4*>(Xv + (size_t)row0 * Fn)[tid];
    }
    // ---- zero K-pad: both tiles, kstep 19, lanes 32..63 ----
    if (tid < 64) {
        const int t = tid >> 5, s = tid & 31;
        half8 z = {0, 0, 0, 0, 0, 0, 0, 0};
        *reinterpret_cast<half8*>(
            sm.g.At + t * TILE_H + (KST - 1) * 512 + 256 + s * 8) = z;
    }
    __syncthreads();

    // ---- gather: 4992 chunk-tasks; chunk c of line j; 4 lanes share a line ----
    // two 5-deep batches to bound VGPR
#pragma unroll
    for (int half_b = 0; half_b < 2; ++half_b) {
        f32x4 v[5];
        float s[5];
        int   slot[5];
        bool  ok[5];
#pragma unroll
        for (int it = 0; it < 5; ++it) {
            const int i = tid + (half_b * 5 + it) * THREADS;
            ok[it] = (i < M * Fn * 4);
            if (ok[it]) {
                const int j = i >> 2, c = i & 3;
                const int r = j & 31, f = j >> 5;
                const int idx = sm.g.xi[r * Fn + f];
                s[it] = sm.g.xv[r * Fn + f];
                const f32x4* src = reinterpret_cast<const f32x4*>(
                    T + ((size_t)f * Vn + (size_t)idx) * En + c * 4);
                v[it] = __builtin_nontemporal_load(src);
                slot[it] = (r >> 4) * TILE_H
                           + (f >> 1) * 512 + (f & 1) * 256 + (r & 15) * 8
                           + (c >> 1) * 128 + (c & 1) * 4;
            }
        }
#pragma unroll
        for (int it = 0; it < 5; ++it) {
            if (ok[it])
                *reinterpret_cast<half4*>(sm.g.At + slot[it]) = cvt4s(v[it], s[it]);
        }
    }
    __syncthreads();

    // ---- GEMM: wave = (q = rowtile, t16 = col-tile) ----
    const int q = wv & 1;
    const int t16 = wv >> 1;
    const int n = t16 * 16 + (lane & 15);
    const int koff = (lane >> 4) * 8;
    const float* wsrc = ((n < 32) ? (w_first + (size_t)n * 624)
                                  : (w_inner + (size_t)(n - 32) * 624));
    const _Float16* aptr = sm.g.At + q * TILE_H + lane * 8;

    floatx4 acc = {0.0f, 0.0f, 0.0f, 0.0f};
#pragma unroll
    for (int t = 0; t < KST; ++t) {
        const half8 af = *reinterpret_cast<const half8*>(aptr + t * 512);
        int kb = t * 32 + koff;
        kb = (kb > 616) ? 616 : kb;   // ragged tail: A pad is zero there
        const float4 w0 = *reinterpret_cast<const float4*>(wsrc + kb);
        const float4 w1 = *reinterpret_cast<const float4*>(wsrc + kb + 4);
        acc = __builtin_amdgcn_mfma_f32_16x16x32_f16(af, cvt8(w0, w1), acc, 0, 0, 0);
    }
    __syncthreads();   // all A reads done; overlay epilogue regions

    // ---- write C tile: col=lane&15, row=(lane>>4)*4+reg ----
    {
        const int col = t16 * 16 + (lane & 15);
        const int rbase = q * 16 + (lane >> 4) * 4;
#pragma unroll
        for (int r = 0; r < 4; ++r)
            sm.e.x[(rbase + r) * 69 + col] = acc[r];
    }

    // ---- stage MLP weights ----
    for (int i = tid; i < 2145; i += THREADS) {
        float v;
        if (i < 1024)      v = lin1_W[i];
        else if (i < 2048) v = lin2_W[i - 1024];
        else if (i < 2080) v = lin1_b[i - 2048];
        else if (i < 2112) v = lin2_b[i - 2080];
        else if (i < 2144) v = last_W[i - 2112];
        else               v = last_b[0];
        sm.e.wsh[i] = v;
    }
    __syncthreads();

    // ---- xin[j][r] = first + s^2 ----
    for (int p = tid; p < 1024; p += THREADS) {
        const int j = p >> 5, r = p & 31;
        const float fi = sm.e.x[r * 69 + j];
        const float sq = sm.e.x[r * 69 + 32 + j];
        sm.e.r1[j * 32 + r] = fi + sq * sq;
    }
    __syncthreads();

    // ---- layer 1 ----
    {
        const int r = tid & 31, n0 = (tid >> 5) * 2;
        float a0 = sm.e.wsh[2048 + n0];
        float a1 = sm.e.wsh[2048 + n0 + 1];
#pragma unroll
        for (int j = 0; j < 32; ++j) {
            const float xj = sm.e.r1[j * 32 + r];
            a0 = fmaf(sm.e.wsh[n0 * 32 + j],       xj, a0);
            a1 = fmaf(sm.e.wsh[(n0 + 1) * 32 + j], xj, a1);
        }
        sm.e.r2[n0 * 32 + r]       = fmaxf(a0, 0.0f);
        sm.e.r2[(n0 + 1) * 32 + r] = fmaxf(a1, 0.0f);
    }
    __syncthreads();

    // ---- layer 2 ----
    {
        const int r = tid & 31, n0 = (tid >> 5) * 2;
        float a0 = sm.e.wsh[2080 + n0];
        float a1 = sm.e.wsh[2080 + n0 + 1];
#pragma unroll
        for (int j = 0; j < 32; ++j) {
            const float xj = sm.e.r2[j * 32 + r];
            a0 = fmaf(sm.e.wsh[1024 + n0 * 32 + j],       xj, a0);
            a1 = fmaf(sm.e.wsh[1024 + (n0 + 1) * 32 + j], xj, a1);
        }
        sm.e.r1[n0 * 32 + r]       = fmaxf(a0, 0.0f);
        sm.e.r1[(n0 + 1) * 32 + r] = fmaxf(a1, 0.0f);
    }
    __syncthreads();

    // ---- last layer + store ----
    if (tid < M) {
        float res = sm.e.wsh[2144];
#pragma unroll
        for (int j = 0; j < 32; ++j)
            res = fmaf(sm.e.wsh[2112 + j], sm.e.r1[j * 32 + tid], res);
        out[row0 + tid] = res;
    }
}

} // namespace

extern "C" void kernel_launch(void* const* d_in, const int* in_sizes, int n_in,
                              void* d_out, int out_size, void* d_ws, size_t ws_size,
                              hipStream_t stream) {
    (void)in_sizes; (void)n_in; (void)out_size; (void)d_ws; (void)ws_size;
    const int*   Xi      = (const int*)d_in[0];
    const float* Xv      = (const float*)d_in[1];
    const float* T       = (const float*)d_in[2];
    const float* w_first = (const float*)d_in[3];
    const float* w_inner = (const float*)d_in[4];
    const float* lin1_W  = (const float*)d_in[5];
    const float* lin1_b  = (const float*)d_in[6];
    const float* lin2_W  = (const float*)d_in[7];
    const float* lin2_b  = (const float*)d_in[8];
    const float* last_W  = (const float*)d_in[9];
    const float* last_b  = (const float*)d_in[10];
    float* out = (float*)d_out;

    hipLaunchKernelGGL(pnn_fused, dim3(Bn / M), dim3(THREADS), 0, stream,
                       Xi, Xv, T, w_first, w_inner,
                       lin1_W, lin1_b, lin2_W, lin2_b, last_W, last_b, out);
}